// Round 1
// baseline (293.165 us; speedup 1.0000x reference)
//
#include <hip/hip_runtime.h>

#define NROWS 4096
#define LV 128
#define H 256
#define D 256
#define K_IN 768   // 3*D
#define LN_EPS 1e-5f
#define BM 8

__global__ __launch_bounds__(256) void coord_compute(
    const float* __restrict__ memory,
    const int*   __restrict__ veh_idx,
    const float* __restrict__ veh_repr,
    const float* __restrict__ cust_repr,
    const float* __restrict__ edge_emb,
    const float* __restrict__ W_in,
    const float* __restrict__ b_in,
    const float* __restrict__ W_h,
    const float* __restrict__ b_h,
    const float* __restrict__ gamma,
    const float* __restrict__ beta,
    float* __restrict__ out)
{
    __shared__ float xs[BM * 1024];
    __shared__ int   idxs[BM];
    __shared__ float red[BM][4][2];

    const int tid  = threadIdx.x;
    const int row0 = blockIdx.x * BM;

    if (tid < BM) idxs[tid] = veh_idx[row0 + tid];

    // stage veh/cust/edge rows: BM*256 floats each = BM*64 float4 each
    const float4* v4 = (const float4*)(veh_repr + (size_t)row0 * D);
    const float4* c4 = (const float4*)(cust_repr + (size_t)row0 * D);
    const float4* e4 = (const float4*)(edge_emb + (size_t)row0 * D);
    for (int i = tid; i < BM * 64; i += 256) {
        int m = i >> 6, c = (i & 63) << 2;
        *(float4*)&xs[m * 1024 + 0   + c] = v4[i];
        *(float4*)&xs[m * 1024 + 256 + c] = c4[i];
        *(float4*)&xs[m * 1024 + 512 + c] = e4[i];
    }
    __syncthreads();  // idxs visible
    for (int i = tid; i < BM * 64; i += 256) {
        int m = i >> 6, c = (i & 63) << 2;
        const float4* src =
            (const float4*)(memory + (size_t)(row0 + m) * LV * H + (size_t)idxs[m] * H);
        *(float4*)&xs[m * 1024 + 768 + c] = src[i & 63];
    }
    __syncthreads();

    const int j = tid;  // output column
    float acc[BM];
#pragma unroll
    for (int m = 0; m < BM; m++) acc[m] = 0.f;

    // x[:, 0:768] @ W_in[:, j]
    for (int k = 0; k < K_IN; k += 4) {
        float w0 = W_in[(k + 0) * H + j];
        float w1 = W_in[(k + 1) * H + j];
        float w2 = W_in[(k + 2) * H + j];
        float w3 = W_in[(k + 3) * H + j];
#pragma unroll
        for (int m = 0; m < BM; m++) {
            float4 xv = *(const float4*)&xs[m * 1024 + k];
            acc[m] += xv.x * w0;
            acc[m] += xv.y * w1;
            acc[m] += xv.z * w2;
            acc[m] += xv.w * w3;
        }
    }
    // cur_h @ W_h[:, j]
    for (int k = 0; k < H; k += 4) {
        float w0 = W_h[(k + 0) * H + j];
        float w1 = W_h[(k + 1) * H + j];
        float w2 = W_h[(k + 2) * H + j];
        float w3 = W_h[(k + 3) * H + j];
#pragma unroll
        for (int m = 0; m < BM; m++) {
            float4 xv = *(const float4*)&xs[m * 1024 + 768 + k];
            acc[m] += xv.x * w0;
            acc[m] += xv.y * w1;
            acc[m] += xv.z * w2;
            acc[m] += xv.w * w3;
        }
    }

    const float bsum = b_in[j] + b_h[j];
#pragma unroll
    for (int m = 0; m < BM; m++) acc[m] += bsum;

    const int lane = tid & 63, wid = tid >> 6;
#pragma unroll
    for (int m = 0; m < BM; m++) {
        float s = acc[m], s2 = acc[m] * acc[m];
#pragma unroll
        for (int off = 32; off; off >>= 1) {
            s  += __shfl_xor(s, off);
            s2 += __shfl_xor(s2, off);
        }
        if (lane == 0) { red[m][wid][0] = s; red[m][wid][1] = s2; }
    }
    __syncthreads();

    const float g = gamma[j], b = beta[j];
#pragma unroll
    for (int m = 0; m < BM; m++) {
        float S  = red[m][0][0] + red[m][1][0] + red[m][2][0] + red[m][3][0];
        float S2 = red[m][0][1] + red[m][1][1] + red[m][2][1] + red[m][3][1];
        float mu   = S * (1.f / H);
        float var  = S2 * (1.f / H) - mu * mu;
        float rstd = rsqrtf(var + LN_EPS);
        float ln   = (acc[m] - mu) * rstd * g + b;
        out[(size_t)(row0 + m) * LV * H + (size_t)idxs[m] * H + j] = tanhf(ln);
    }
}

extern "C" void kernel_launch(void* const* d_in, const int* in_sizes, int n_in,
                              void* d_out, int out_size, void* d_ws, size_t ws_size,
                              hipStream_t stream) {
    const float* memory    = (const float*)d_in[0];
    const int*   veh_idx   = (const int*)d_in[1];
    const float* veh_repr  = (const float*)d_in[2];
    const float* cust_repr = (const float*)d_in[3];
    const float* edge_emb  = (const float*)d_in[4];
    const float* W_in      = (const float*)d_in[5];
    const float* b_in      = (const float*)d_in[6];
    const float* W_h       = (const float*)d_in[7];
    const float* b_h       = (const float*)d_in[8];
    const float* gamma     = (const float*)d_in[9];
    const float* beta      = (const float*)d_in[10];
    float* out = (float*)d_out;

    const size_t bytes = (size_t)NROWS * LV * H * sizeof(float);
    hipMemcpyAsync(d_out, d_in[0], bytes, hipMemcpyDeviceToDevice, stream);

    coord_compute<<<NROWS / BM, 256, 0, stream>>>(
        memory, veh_idx, veh_repr, cust_repr, edge_emb,
        W_in, b_in, W_h, b_h, gamma, beta, out);
}

// Round 2
// 213.123 us; speedup vs baseline: 1.3756x; 1.3756x over previous
//
#include <hip/hip_runtime.h>

#define NROWS 4096
#define LV 128
#define H 256
#define D 256
#define K_IN 768   // 3*D
#define LN_EPS 1e-5f
#define BM 8

#define COMPUTE_BLOCKS (NROWS / BM)   // 512
#define COPY_BLOCKS    2048           // 4 waves each; wave = half an n-slab (64 rows)

__global__ __launch_bounds__(256) void coord_fused(
    const float* __restrict__ memory,
    const int*   __restrict__ veh_idx,
    const float* __restrict__ veh_repr,
    const float* __restrict__ cust_repr,
    const float* __restrict__ edge_emb,
    const float* __restrict__ W_in,
    const float* __restrict__ b_in,
    const float* __restrict__ W_h,
    const float* __restrict__ b_h,
    const float* __restrict__ gamma,
    const float* __restrict__ beta,
    float* __restrict__ out)
{
    __shared__ float xs[BM * 1024];
    __shared__ int   idxs[BM];
    __shared__ float red[BM][4][2];

    const int tid = threadIdx.x;

    if (blockIdx.x >= COMPUTE_BLOCKS) {
        // ---------------- copy path: all (n, l != idx[n]) rows ----------------
        const int cb   = blockIdx.x - COMPUTE_BLOCKS;
        const int wid  = tid >> 6;
        const int lane = tid & 63;
        const int w    = cb * 4 + wid;      // 0..8191
        const int n    = w >> 1;            // 0..4095
        const int l0   = (w & 1) * 64;      // half-slab
        const int idxn = veh_idx[n];

        const size_t base = ((size_t)n * LV + l0) * H + (size_t)lane * 4;
        const float4* src = (const float4*)(memory + base);
        float4*       dst = (float4*)(out + base);

        for (int l = 0; l < 64; l += 4) {
            float4 v0 = src[(size_t)(l + 0) * 64];
            float4 v1 = src[(size_t)(l + 1) * 64];
            float4 v2 = src[(size_t)(l + 2) * 64];
            float4 v3 = src[(size_t)(l + 3) * 64];
            if (l0 + l + 0 != idxn) dst[(size_t)(l + 0) * 64] = v0;
            if (l0 + l + 1 != idxn) dst[(size_t)(l + 1) * 64] = v1;
            if (l0 + l + 2 != idxn) dst[(size_t)(l + 2) * 64] = v2;
            if (l0 + l + 3 != idxn) dst[(size_t)(l + 3) * 64] = v3;
        }
        return;
    }

    // ---------------- compute path: the (n, idx[n]) rows ----------------
    const int row0 = blockIdx.x * BM;

    if (tid < BM) idxs[tid] = veh_idx[row0 + tid];

    const float4* v4 = (const float4*)(veh_repr + (size_t)row0 * D);
    const float4* c4 = (const float4*)(cust_repr + (size_t)row0 * D);
    const float4* e4 = (const float4*)(edge_emb + (size_t)row0 * D);
    for (int i = tid; i < BM * 64; i += 256) {
        int m = i >> 6, c = (i & 63) << 2;
        *(float4*)&xs[m * 1024 + 0   + c] = v4[i];
        *(float4*)&xs[m * 1024 + 256 + c] = c4[i];
        *(float4*)&xs[m * 1024 + 512 + c] = e4[i];
    }
    __syncthreads();  // idxs visible
    for (int i = tid; i < BM * 64; i += 256) {
        int m = i >> 6, c = (i & 63) << 2;
        const float4* src =
            (const float4*)(memory + (size_t)(row0 + m) * LV * H + (size_t)idxs[m] * H);
        *(float4*)&xs[m * 1024 + 768 + c] = src[i & 63];
    }
    __syncthreads();

    const int j = tid;  // output column
    float acc[BM];
#pragma unroll
    for (int m = 0; m < BM; m++) acc[m] = 0.f;

    for (int k = 0; k < K_IN; k += 4) {
        float w0 = W_in[(k + 0) * H + j];
        float w1 = W_in[(k + 1) * H + j];
        float w2 = W_in[(k + 2) * H + j];
        float w3 = W_in[(k + 3) * H + j];
#pragma unroll
        for (int m = 0; m < BM; m++) {
            float4 xv = *(const float4*)&xs[m * 1024 + k];
            acc[m] += xv.x * w0;
            acc[m] += xv.y * w1;
            acc[m] += xv.z * w2;
            acc[m] += xv.w * w3;
        }
    }
    for (int k = 0; k < H; k += 4) {
        float w0 = W_h[(k + 0) * H + j];
        float w1 = W_h[(k + 1) * H + j];
        float w2 = W_h[(k + 2) * H + j];
        float w3 = W_h[(k + 3) * H + j];
#pragma unroll
        for (int m = 0; m < BM; m++) {
            float4 xv = *(const float4*)&xs[m * 1024 + 768 + k];
            acc[m] += xv.x * w0;
            acc[m] += xv.y * w1;
            acc[m] += xv.z * w2;
            acc[m] += xv.w * w3;
        }
    }

    const float bsum = b_in[j] + b_h[j];
#pragma unroll
    for (int m = 0; m < BM; m++) acc[m] += bsum;

    const int lane = tid & 63, wid = tid >> 6;
#pragma unroll
    for (int m = 0; m < BM; m++) {
        float s = acc[m], s2 = acc[m] * acc[m];
#pragma unroll
        for (int off = 32; off; off >>= 1) {
            s  += __shfl_xor(s, off);
            s2 += __shfl_xor(s2, off);
        }
        if (lane == 0) { red[m][wid][0] = s; red[m][wid][1] = s2; }
    }
    __syncthreads();

    const float g = gamma[j], b = beta[j];
#pragma unroll
    for (int m = 0; m < BM; m++) {
        float S  = red[m][0][0] + red[m][1][0] + red[m][2][0] + red[m][3][0];
        float S2 = red[m][0][1] + red[m][1][1] + red[m][2][1] + red[m][3][1];
        float mu   = S * (1.f / H);
        float var  = S2 * (1.f / H) - mu * mu;
        float rstd = rsqrtf(var + LN_EPS);
        float ln   = (acc[m] - mu) * rstd * g + b;
        out[(size_t)(row0 + m) * LV * H + (size_t)idxs[m] * H + j] = tanhf(ln);
    }
}

extern "C" void kernel_launch(void* const* d_in, const int* in_sizes, int n_in,
                              void* d_out, int out_size, void* d_ws, size_t ws_size,
                              hipStream_t stream) {
    const float* memory    = (const float*)d_in[0];
    const int*   veh_idx   = (const int*)d_in[1];
    const float* veh_repr  = (const float*)d_in[2];
    const float* cust_repr = (const float*)d_in[3];
    const float* edge_emb  = (const float*)d_in[4];
    const float* W_in      = (const float*)d_in[5];
    const float* b_in      = (const float*)d_in[6];
    const float* W_h       = (const float*)d_in[7];
    const float* b_h       = (const float*)d_in[8];
    const float* gamma     = (const float*)d_in[9];
    const float* beta      = (const float*)d_in[10];
    float* out = (float*)d_out;

    coord_fused<<<COMPUTE_BLOCKS + COPY_BLOCKS, 256, 0, stream>>>(
        memory, veh_idx, veh_repr, cust_repr, edge_emb,
        W_in, b_in, W_h, b_h, gamma, beta, out);
}